// Round 3
// baseline (599.701 us; speedup 1.0000x reference)
//
#include <hip/hip_runtime.h>

// Forward-fill (LOCF) along L for x:(B,L,N) fp32, NaN = missing.
// Outputs: x_filled (B*L*N fp32) then mask as 0.0/1.0 fp32, concatenated.
//
// R7 (this round): SINGLE-PASS fused kernel with decoupled lookback
// (rocPRIM-style). Rationale: R0/R1/R2 all moved ~560 MB at a constant
// ~1.3 TB/s regardless of structure (436.8 / 445.1 / 428.1 us) while the
// harness fillBuffer hit 6.6 TB/s in the same capture -> we are per-byte
// limited, not structure limited. This version:
//   - reads x ONCE (held in registers; -134 MB vs 3-kernel version)
//   - writes out+mask with PLAIN cached stores (NT stores never ablated;
//     their only justification -- protecting L3 for the x re-read -- is
//     gone now that there is no re-read)
//   - block carry via decoupled lookback over predecessor segments of the
//     same series. At 80% observation density a 64-row block has ~zero
//     probability of an all-NaN channel, so lookback terminates at depth 1
//     on the predecessor's AGGREGATE (no serial chain, no flag==2 wait).
//   - flags zeroed per launch by an 8 KB hipMemsetAsync (graph-capturable).
//
// R6 lesson: register-staging all chunk loads (4x MLP) was neutral -> not
// latency-limited at the wave level.
// R5 lesson: carry-loop removal was neutral -> streaming phases dominate.
// R3 lesson: nt LOADS on x prevented L3 allocation (+40 us). (nt stores
// are ablated THIS round.)
// R2 lesson: __builtin_nontemporal_* requires clang ext_vector_type.

typedef float floatx4 __attribute__((ext_vector_type(4)));

constexpr int B = 32, L = 4096, N = 256;
constexpr int N4 = N / 4;            // 64 float4 lanes across channels = 1 wave
constexpr int ROWS_PER_WAVE = 16;
constexpr int WAVES = 4;             // 256 threads
constexpr int ROWS_PER_BLK = ROWS_PER_WAVE * WAVES;   // 64
constexpr int SEG = L / ROWS_PER_BLK;                 // 64 segments per series
constexpr int NBLK = B * SEG;                         // 2048 blocks

__device__ __forceinline__ float dev_nan() { return __int_as_float(0x7fc00000); }
__device__ __forceinline__ floatx4 nan4() {
    return floatx4{dev_nan(), dev_nan(), dev_nan(), dev_nan()};
}

// last[c] = v[c] if v[c] observed (non-NaN) else last[c]   (v is NEWER)
__device__ __forceinline__ void upd(floatx4& last, const floatx4 v) {
    last.x = (v.x == v.x) ? v.x : last.x;
    last.y = (v.y == v.y) ? v.y : last.y;
    last.z = (v.z == v.z) ? v.z : last.z;
    last.w = (v.w == v.w) ? v.w : last.w;
}

// acc[c] = acc[c] if observed else older[c]   (older is EARLIER in time)
__device__ __forceinline__ void updOlder(floatx4& acc, const floatx4 older) {
    acc.x = (acc.x == acc.x) ? acc.x : older.x;
    acc.y = (acc.y == acc.y) ? acc.y : older.y;
    acc.z = (acc.z == acc.z) ? acc.z : older.z;
    acc.w = (acc.w == acc.w) ? acc.w : older.w;
}

__device__ __forceinline__ int ld_acq(const int* p) {
    return __hip_atomic_load(p, __ATOMIC_ACQUIRE, __HIP_MEMORY_SCOPE_AGENT);
}
__device__ __forceinline__ void st_rel(int* p, int v) {
    __hip_atomic_store(p, v, __ATOMIC_RELEASE, __HIP_MEMORY_SCOPE_AGENT);
}

// flags: 0 = nothing, 1 = aggregate published, 2 = inclusive prefix published.
__global__ __launch_bounds__(256) void k_fused(const floatx4* __restrict__ x4,
                                               floatx4* __restrict__ out4,
                                               floatx4* __restrict__ m4,
                                               int* __restrict__ flags,
                                               floatx4* __restrict__ agg4,
                                               floatx4* __restrict__ incl4) {
    const int blk  = blockIdx.x;
    const int b    = blk / SEG;
    const int s    = blk % SEG;          // segment along L
    const int w    = threadIdx.x >> 6;   // wave within block
    const int lane = threadIdx.x & 63;   // n4 index

    __shared__ floatx4 lds_tail[WAVES][N4];
    __shared__ floatx4 lds_carry[N4];

    // ---- Phase 1: load this wave's 16 rows into registers (max MLP), tail.
    const long base =
        ((long)b * L + (long)s * ROWS_PER_BLK + (long)w * ROWS_PER_WAVE) * N4 + lane;
    floatx4 v[ROWS_PER_WAVE];
#pragma unroll
    for (int i = 0; i < ROWS_PER_WAVE; ++i) v[i] = x4[base + (long)i * N4];

    floatx4 tail = nan4();
#pragma unroll
    for (int i = 0; i < ROWS_PER_WAVE; ++i) upd(tail, v[i]);
    lds_tail[w][lane] = tail;
    __syncthreads();

    // ---- Phase 2 (wave 0 only): block aggregate, publish, lookback.
    if (w == 0) {
        floatx4 agg = lds_tail[0][lane];
        upd(agg, lds_tail[1][lane]);
        upd(agg, lds_tail[2][lane]);
        upd(agg, lds_tail[3][lane]);

        floatx4 carry;
        if (s == 0) {
            incl4[(long)blk * N4 + lane] = agg;
            st_rel(&flags[blk], 2);
            carry = nan4();
        } else {
            agg4[(long)blk * N4 + lane] = agg;
            st_rel(&flags[blk], 1);

            floatx4 suf = nan4();          // combine of tails (j+1 .. s-1)
            int j = s - 1;
            for (;;) {
                const int f = ld_acq(&flags[b * SEG + j]);
                if (f == 2) {
                    updOlder(suf, incl4[(long)(b * SEG + j) * N4 + lane]);
                    break;
                } else if (f == 1) {
                    updOlder(suf, agg4[(long)(b * SEG + j) * N4 + lane]);
                    const int full = (suf.x == suf.x) && (suf.y == suf.y) &&
                                     (suf.z == suf.z) && (suf.w == suf.w);
                    if (__all(full) || j == 0) break;  // j==0 always ends at f==2;
                    --j;                               // guard is belt-and-braces
                } else {
                    __builtin_amdgcn_s_sleep(1);
                }
            }
            carry = suf;

            floatx4 incl = carry;
            upd(incl, agg);                 // agg is newer than the carry
            incl4[(long)blk * N4 + lane] = incl;
            st_rel(&flags[blk], 2);
        }
        lds_carry[lane] = carry;
    }
    __syncthreads();

    // ---- Phase 3: wave-local carry, fill from registers, plain stores.
    floatx4 last = lds_carry[lane];
    for (int ww = 0; ww < w; ++ww) upd(last, lds_tail[ww][lane]);

#pragma unroll
    for (int i = 0; i < ROWS_PER_WAVE; ++i) {
        const long idx = base + (long)i * N4;
        const floatx4 val = v[i];
        upd(last, val);
        floatx4 o;
        o.x = (last.x == last.x) ? last.x : 0.0f;
        o.y = (last.y == last.y) ? last.y : 0.0f;
        o.z = (last.z == last.z) ? last.z : 0.0f;
        o.w = (last.w == last.w) ? last.w : 0.0f;
        out4[idx] = o;
        if (m4) {
            floatx4 m = {(val.x == val.x) ? 1.0f : 0.0f,
                         (val.y == val.y) ? 1.0f : 0.0f,
                         (val.z == val.z) ? 1.0f : 0.0f,
                         (val.w == val.w) ? 1.0f : 0.0f};
            m4[idx] = m;
        }
    }
}

// ---------- legacy 2-kernel fallback (tiny workspace only) ----------

template <int LC>
__global__ __launch_bounds__(256) void k_tail(const floatx4* __restrict__ x4,
                                              floatx4* __restrict__ tail4) {
    constexpr int C = L / LC;
    const int gid   = blockIdx.x;
    const int b     = gid / (C / 4);
    const int chunk = (gid % (C / 4)) * 4 + (threadIdx.x >> 6);
    const int n4    = threadIdx.x & 63;
    const floatx4* p = x4 + (long)(b * L + chunk * LC) * N4 + n4;
    floatx4 last = nan4();
#pragma unroll 8
    for (int i = 0; i < LC; ++i) upd(last, p[(long)i * N4]);
    tail4[(long)(b * C + chunk) * N4 + n4] = last;
}

template <int LC>
__global__ __launch_bounds__(256) void k_fill_legacy(const floatx4* __restrict__ x4,
                                                     const floatx4* __restrict__ t4,
                                                     floatx4* __restrict__ out4,
                                                     floatx4* __restrict__ m4) {
    constexpr int C = L / LC;
    const int gid   = blockIdx.x;
    const int b     = gid / (C / 4);
    const int chunk = (gid % (C / 4)) * 4 + (threadIdx.x >> 6);
    const int n4    = threadIdx.x & 63;

    floatx4 last = nan4();
    const floatx4* tb = t4 + (long)b * C * N4 + n4;
    for (int j = 0; j < chunk; ++j) upd(last, tb[(long)j * N4]);

    const long base = (long)(b * L + chunk * LC) * N4 + n4;
#pragma unroll 4
    for (int i = 0; i < LC; ++i) {
        const long idx = base + (long)i * N4;
        const floatx4 val = x4[idx];
        upd(last, val);
        floatx4 o;
        o.x = (last.x == last.x) ? last.x : 0.0f;
        o.y = (last.y == last.y) ? last.y : 0.0f;
        o.z = (last.z == last.z) ? last.z : 0.0f;
        o.w = (last.w == last.w) ? last.w : 0.0f;
        out4[idx] = o;
        if (m4) {
            floatx4 m = {(val.x == val.x) ? 1.0f : 0.0f,
                         (val.y == val.y) ? 1.0f : 0.0f,
                         (val.z == val.z) ? 1.0f : 0.0f,
                         (val.w == val.w) ? 1.0f : 0.0f};
            m4[idx] = m;
        }
    }
}

extern "C" void kernel_launch(void* const* d_in, const int* in_sizes, int n_in,
                              void* d_out, int out_size, void* d_ws, size_t ws_size,
                              hipStream_t stream) {
    const float* x = (const float*)d_in[0];
    const long n_total = (long)B * L * N;  // 33,554,432

    float* out = (float*)d_out;
    float* mask_out = ((long)out_size >= 2 * n_total) ? out + n_total : nullptr;

    // ws layout for fused path: flags[NBLK] (8 KB), agg (2 MB), incl (2 MB).
    const size_t flags_bytes = (size_t)NBLK * sizeof(int);
    const size_t payl_bytes  = (size_t)NBLK * N * sizeof(float);
    const size_t need        = flags_bytes + 2 * payl_bytes;

    if (ws_size >= need) {
        char* p      = (char*)d_ws;
        int*  flags  = (int*)p;
        floatx4* agg  = (floatx4*)(p + flags_bytes);
        floatx4* incl = (floatx4*)(p + flags_bytes + payl_bytes);
        hipMemsetAsync(flags, 0, flags_bytes, stream);   // graph-capturable
        k_fused<<<NBLK, 256, 0, stream>>>((const floatx4*)x, (floatx4*)out,
                                          (floatx4*)mask_out, flags, agg, incl);
    } else {
        // Tiny-workspace fallback: 2-kernel chunked scan, LC=128 (1 MB tails).
        constexpr int LC = 128, C = L / LC;
        float* tail = (float*)d_ws;
        k_tail<LC><<<B * C / 4, 256, 0, stream>>>((const floatx4*)x,
                                                  (floatx4*)tail);
        k_fill_legacy<LC><<<B * C / 4, 256, 0, stream>>>((const floatx4*)x,
                                                         (const floatx4*)tail,
                                                         (floatx4*)out,
                                                         (floatx4*)mask_out);
    }
}

// Round 4
// 542.126 us; speedup vs baseline: 1.1062x; 1.1062x over previous
//
#include <hip/hip_runtime.h>

// Forward-fill (LOCF) along L for x:(B,L,N) fp32, NaN = missing.
// Outputs: x_filled (B*L*N fp32) then mask as 0.0/1.0 fp32, concatenated.
//
// R8 (this round): TWO-PASS, SINGLE-READ, NO ATOMICS.
//   k_prefix     : per (b,chunk,n) within-chunk LOCF prefix. Writes out+mask
//                  DIRECTLY (0 before chunk's first obs), plus chunk tail and
//                  per-channel first-obs index (uint8x4 packed per lane).
//                  x is read EXACTLY ONCE kernel-wide (-134 MB vs R2).
//   k_scan_patch : one wave per series walks chunk tails (register-staged),
//                  carry in registers, and PATCHES the ~0.25 rows/chunk-channel
//                  that precede each chunk's first observation (~2 MB of
//                  scattered 4B stores). No carry array, no 3rd kernel.
//   Plain cached stores everywhere (ablates NT stores: fillBuffer hits
//   6.6 TB/s with cached stores; nothing needs L3 protection now).
//
// R7 lesson (k_fused counters: VALUBusy 2.5%, HBM 14%, 300 us): decoupled
// lookback's agent-scope acquire/release = buffer_inv / buffer_wbl2 -> each
// of 2048 blocks invalidates/writes-back a whole XCD L2 -> cache-maintenance
// storm destroys streaming. NEVER cross-block-sync a streaming kernel here.
// R7 lesson 2: bench dur_us ~ 2x sum(dispatch times) -> optimize dispatch sum.
// R6 lesson: register-staging (4x MLP) neutral -> not wave-MLP-limited.
// R5 lesson: carry-loop removal neutral -> streaming phases dominate.
// R3 lesson: nt LOADS on x prevented L3 allocation (+40 us).
// R2 lesson: __builtin_nontemporal_* requires clang ext_vector_type.

typedef float floatx4 __attribute__((ext_vector_type(4)));

constexpr int B = 32, L = 4096, N = 256;
constexpr int N4 = N / 4;   // 64 float4 lanes across channels == one wave
constexpr int CPB = 4;      // chunks per 256-thread block (one wave per chunk)

__device__ __forceinline__ float dev_nan() { return __int_as_float(0x7fc00000); }
__device__ __forceinline__ floatx4 nan4() {
    return floatx4{dev_nan(), dev_nan(), dev_nan(), dev_nan()};
}

// last[c] = v[c] if v[c] observed (non-NaN) else last[c]   (v is NEWER)
__device__ __forceinline__ void upd(floatx4& last, const floatx4 v) {
    last.x = (v.x == v.x) ? v.x : last.x;
    last.y = (v.y == v.y) ? v.y : last.y;
    last.z = (v.z == v.z) ? v.z : last.z;
    last.w = (v.w == v.w) ? v.w : last.w;
}

// Pass 1: within-chunk prefix fill + tail + first-obs indices.
template <int LC>
__global__ __launch_bounds__(256) void k_prefix(const floatx4* __restrict__ x4,
                                                floatx4* __restrict__ out4,
                                                floatx4* __restrict__ m4,
                                                floatx4* __restrict__ tail4,
                                                unsigned int* __restrict__ fo) {
    constexpr int C = L / LC;
    const int gid   = blockIdx.x;
    const int b     = gid / (C / CPB);
    const int chunk = (gid % (C / CPB)) * CPB + (threadIdx.x >> 6);
    const int lane  = threadIdx.x & 63;

    const long base = (long)(b * L + chunk * LC) * N4 + lane;
    floatx4 last = nan4();
    int f0 = LC, f1 = LC, f2 = LC, f3 = LC;   // first-obs index per channel

    for (int g = 0; g < LC; g += 8) {
        floatx4 v[8];
#pragma unroll
        for (int i = 0; i < 8; ++i) v[i] = x4[base + (long)(g + i) * N4];
#pragma unroll
        for (int i = 0; i < 8; ++i) {
            const floatx4 val = v[i];
            const bool ox = (val.x == val.x);
            const bool oy = (val.y == val.y);
            const bool oz = (val.z == val.z);
            const bool ow = (val.w == val.w);
            if (ox && f0 == LC) f0 = g + i;   // cndmask, no branch
            if (oy && f1 == LC) f1 = g + i;
            if (oz && f2 == LC) f2 = g + i;
            if (ow && f3 == LC) f3 = g + i;
            upd(last, val);
            floatx4 o;
            o.x = (last.x == last.x) ? last.x : 0.0f;
            o.y = (last.y == last.y) ? last.y : 0.0f;
            o.z = (last.z == last.z) ? last.z : 0.0f;
            o.w = (last.w == last.w) ? last.w : 0.0f;
            const long idx = base + (long)(g + i) * N4;
            out4[idx] = o;                      // plain cached store
            if (m4) {
                floatx4 m = {ox ? 1.0f : 0.0f, oy ? 1.0f : 0.0f,
                             oz ? 1.0f : 0.0f, ow ? 1.0f : 0.0f};
                m4[idx] = m;
            }
        }
    }
    tail4[(long)(b * C + chunk) * N4 + lane] = last;
    fo[(long)(b * C + chunk) * 64 + lane] =
        (unsigned)f0 | ((unsigned)f1 << 8) | ((unsigned)f2 << 16) |
        ((unsigned)f3 << 24);
}

// Pass 2: per series, sequential scan of chunk tails (carry in registers),
// patching rows before each chunk's first observation with the carry value.
// Rows with no prior observation stay 0 (k_prefix already wrote 0). Mask
// needs no patch. ~2 MB of scattered stores total; one wave per series.
template <int LC>
__global__ __launch_bounds__(64) void k_scan_patch(const floatx4* __restrict__ tail4,
                                                   const unsigned int* __restrict__ fo,
                                                   float* __restrict__ out) {
    constexpr int C = L / LC;
    constexpr int G = (C < 16) ? C : 16;      // staging group
    const int b    = blockIdx.x;              // grid = B
    const int lane = threadIdx.x;             // one wave

    const floatx4*      t  = tail4 + (long)b * C * N4 + lane;
    const unsigned int* fp = fo    + (long)b * C * 64 + lane;

    floatx4 carry = nan4();
    for (int g = 0; g < C; g += G) {
        floatx4      tv[G];
        unsigned int fv[G];
#pragma unroll
        for (int j = 0; j < G; ++j) {
            tv[j] = t[(long)(g + j) * N4];
            fv[j] = fp[(long)(g + j) * 64];
        }
#pragma unroll
        for (int j = 0; j < G; ++j) {
            const int chunk = g + j;
            const unsigned fw = fv[j];
            const int f0 = fw & 255, f1 = (fw >> 8) & 255;
            const int f2 = (fw >> 16) & 255, f3 = fw >> 24;
            const bool c0 = (carry.x == carry.x);
            const bool c1 = (carry.y == carry.y);
            const bool c2 = (carry.z == carry.z);
            const bool c3 = (carry.w == carry.w);
            int pm = 0;
            if (c0) pm = max(pm, f0);
            if (c1) pm = max(pm, f1);
            if (c2) pm = max(pm, f2);
            if (c3) pm = max(pm, f3);
            if (pm > 0) {
                float* op = out + (long)(b * L + chunk * LC) * N + lane * 4;
                for (int i = 0; i < pm; ++i) {
                    if (c0 && i < f0) op[(long)i * N + 0] = carry.x;
                    if (c1 && i < f1) op[(long)i * N + 1] = carry.y;
                    if (c2 && i < f2) op[(long)i * N + 2] = carry.z;
                    if (c3 && i < f3) op[(long)i * N + 3] = carry.w;
                }
            }
            upd(carry, tv[j]);
        }
    }
}

template <int LC>
static void run_all(const float* x, float* out, float* mask_out, void* d_ws,
                    hipStream_t stream) {
    constexpr int C = L / LC;
    floatx4*      tail = (floatx4*)d_ws;
    unsigned int* fo   = (unsigned int*)((char*)d_ws + (size_t)B * C * N * 4);
    k_prefix<LC><<<B * C / CPB, 256, 0, stream>>>((const floatx4*)x,
                                                  (floatx4*)out,
                                                  (floatx4*)mask_out,
                                                  tail, fo);
    k_scan_patch<LC><<<B, 64, 0, stream>>>(tail, fo, out);
}

extern "C" void kernel_launch(void* const* d_in, const int* in_sizes, int n_in,
                              void* d_out, int out_size, void* d_ws, size_t ws_size,
                              hipStream_t stream) {
    const float* x = (const float*)d_in[0];
    const long n_total = (long)B * L * N;  // 33,554,432

    float* out = (float*)d_out;
    float* mask_out = ((long)out_size >= 2 * n_total) ? out + n_total : nullptr;

    // ws need per LC: tails (B*C*N*4 B) + first-obs (B*C*N B) = B*C*N*5.
    auto need = [](int C) { return (size_t)B * C * N * 5; };

    if (ws_size >= need(L / 16)) {
        // LC=16 (C=256): 10.5 MB ws, 2048-block pass-1 grid (8 blocks/CU).
        run_all<16>(x, out, mask_out, d_ws, stream);
    } else if (ws_size >= need(L / 32)) {
        run_all<32>(x, out, mask_out, d_ws, stream);   // 5.2 MB
    } else if (ws_size >= need(L / 128)) {
        run_all<128>(x, out, mask_out, d_ws, stream);  // 1.3 MB
    } else {
        run_all<1024>(x, out, mask_out, d_ws, stream); // 160 KB, last resort
    }
}

// Round 5
// 455.403 us; speedup vs baseline: 1.3169x; 1.1904x over previous
//
#include <hip/hip_runtime.h>

// Forward-fill (LOCF) along L for x:(B,L,N) fp32, NaN = missing.
// Outputs: x_filled (B*L*N fp32) then mask as 0.0/1.0 fp32, concatenated.
//
// R9 (this round): prefix+patch structure (single x read, no atomics) with
//   (a) NT stores RESTORED on out+mask. Five-round pattern: every NT version
//       ~430 us, every cached version ~550-600 us. NT helps the 268 MB write
//       stream directly (not via L3 protection as previously theorized).
//   (b) FEWER, LONGER STREAMS: LC=64 -> 512 blocks / 2048 waves, each wave
//       streams a contiguous 64 KB run per array. fillBuffer hits 6.5 TB/s
//       with ~1024 waves at 9.5% occupancy; our previous 4-8K waves x 3
//       arrays = ~24K interleaved sequential streams = DRAM row-buffer
//       thrash. This is the hypothesis for why ALL structure changes were
//       neutral at ~1.3-2.5 TB/s effective.
//   (c) stores batched 8-per-stream so NT stores issue back-to-back.
//
// R8 lesson: single-read + cached stores = 542 (worse than R2's 428).
// R7 lesson: agent-scope acquire/release in a streaming kernel = L2
//   cache-maintenance storm (VALUBusy 2.5%, HBM 14%). Never again.
// R6 lesson: register-staging loads (4x MLP) neutral.
// R5 lesson: carry-loop removal neutral.
// R3 lesson: nt LOADS on x prevented L3 allocation (+40 us) - loads stay cached.
// R2 lesson: __builtin_nontemporal_* requires clang ext_vector_type.

typedef float floatx4 __attribute__((ext_vector_type(4)));

constexpr int B = 32, L = 4096, N = 256;
constexpr int N4 = N / 4;   // 64 float4 lanes across channels == one wave
constexpr int CPB = 4;      // chunks per 256-thread block (one wave per chunk)

__device__ __forceinline__ float dev_nan() { return __int_as_float(0x7fc00000); }
__device__ __forceinline__ floatx4 nan4() {
    return floatx4{dev_nan(), dev_nan(), dev_nan(), dev_nan()};
}

// last[c] = v[c] if v[c] observed (non-NaN) else last[c]   (v is NEWER)
__device__ __forceinline__ void upd(floatx4& last, const floatx4 v) {
    last.x = (v.x == v.x) ? v.x : last.x;
    last.y = (v.y == v.y) ? v.y : last.y;
    last.z = (v.z == v.z) ? v.z : last.z;
    last.w = (v.w == v.w) ? v.w : last.w;
}

// Pass 1: within-chunk prefix fill + tail + first-obs indices.
// Each wave owns one chunk of LC rows = LC KB contiguous per array.
template <int LC>
__global__ __launch_bounds__(256) void k_prefix(const floatx4* __restrict__ x4,
                                                floatx4* __restrict__ out4,
                                                floatx4* __restrict__ m4,
                                                floatx4* __restrict__ tail4,
                                                unsigned int* __restrict__ fo) {
    constexpr int C = L / LC;
    const int gid   = blockIdx.x;
    const int b     = gid / (C / CPB);
    const int chunk = (gid % (C / CPB)) * CPB + (threadIdx.x >> 6);
    const int lane  = threadIdx.x & 63;

    const long base = (long)(b * L + chunk * LC) * N4 + lane;
    floatx4 last = nan4();
    int f0 = LC, f1 = LC, f2 = LC, f3 = LC;   // first-obs index per channel

    for (int g = 0; g < LC; g += 8) {
        // Stage 8 rows of loads (cached: x may be L3-resident).
        floatx4 v[8];
#pragma unroll
        for (int i = 0; i < 8; ++i) v[i] = x4[base + (long)(g + i) * N4];

        // Serial prefix over the 8 rows into o[].
        floatx4 o[8];
#pragma unroll
        for (int i = 0; i < 8; ++i) {
            const floatx4 val = v[i];
            if ((val.x == val.x) && f0 == LC) f0 = g + i;   // cndmask
            if ((val.y == val.y) && f1 == LC) f1 = g + i;
            if ((val.z == val.z) && f2 == LC) f2 = g + i;
            if ((val.w == val.w) && f3 == LC) f3 = g + i;
            upd(last, val);
            o[i].x = (last.x == last.x) ? last.x : 0.0f;
            o[i].y = (last.y == last.y) ? last.y : 0.0f;
            o[i].z = (last.z == last.z) ? last.z : 0.0f;
            o[i].w = (last.w == last.w) ? last.w : 0.0f;
        }

        // Batched NT stores: 8 back-to-back per stream.
#pragma unroll
        for (int i = 0; i < 8; ++i)
            __builtin_nontemporal_store(o[i], out4 + base + (long)(g + i) * N4);
        if (m4) {
#pragma unroll
            for (int i = 0; i < 8; ++i) {
                const floatx4 val = v[i];
                floatx4 m = {(val.x == val.x) ? 1.0f : 0.0f,
                             (val.y == val.y) ? 1.0f : 0.0f,
                             (val.z == val.z) ? 1.0f : 0.0f,
                             (val.w == val.w) ? 1.0f : 0.0f};
                __builtin_nontemporal_store(m, m4 + base + (long)(g + i) * N4);
            }
        }
    }
    tail4[(long)(b * C + chunk) * N4 + lane] = last;
    fo[(long)(b * C + chunk) * 64 + lane] =
        (unsigned)f0 | ((unsigned)f1 << 8) | ((unsigned)f2 << 16) |
        ((unsigned)f3 << 24);
}

// Pass 2: per series, sequential scan of chunk tails (carry in registers),
// patching the few rows that precede each chunk's first observation with the
// carry value. Rows with no prior observation anywhere stay 0. Mask needs no
// patch. One wave per series; scattered 4B plain stores (~2 MB total).
template <int LC>
__global__ __launch_bounds__(64) void k_scan_patch(const floatx4* __restrict__ tail4,
                                                   const unsigned int* __restrict__ fo,
                                                   float* __restrict__ out) {
    constexpr int C = L / LC;
    constexpr int G = (C < 16) ? C : 16;      // staging group
    const int b    = blockIdx.x;              // grid = B
    const int lane = threadIdx.x;             // one wave

    const floatx4*      t  = tail4 + (long)b * C * N4 + lane;
    const unsigned int* fp = fo    + (long)b * C * 64 + lane;

    floatx4 carry = nan4();
    for (int g = 0; g < C; g += G) {
        floatx4      tv[G];
        unsigned int fv[G];
#pragma unroll
        for (int j = 0; j < G; ++j) {
            tv[j] = t[(long)(g + j) * N4];
            fv[j] = fp[(long)(g + j) * 64];
        }
#pragma unroll
        for (int j = 0; j < G; ++j) {
            const int chunk = g + j;
            const unsigned fw = fv[j];
            const int f0 = fw & 255, f1 = (fw >> 8) & 255;
            const int f2 = (fw >> 16) & 255, f3 = fw >> 24;
            const bool c0 = (carry.x == carry.x);
            const bool c1 = (carry.y == carry.y);
            const bool c2 = (carry.z == carry.z);
            const bool c3 = (carry.w == carry.w);
            int pm = 0;
            if (c0) pm = max(pm, f0);
            if (c1) pm = max(pm, f1);
            if (c2) pm = max(pm, f2);
            if (c3) pm = max(pm, f3);
            if (pm > 0) {
                float* op = out + (long)(b * L + chunk * LC) * N + lane * 4;
                for (int i = 0; i < pm; ++i) {
                    if (c0 && i < f0) op[(long)i * N + 0] = carry.x;
                    if (c1 && i < f1) op[(long)i * N + 1] = carry.y;
                    if (c2 && i < f2) op[(long)i * N + 2] = carry.z;
                    if (c3 && i < f3) op[(long)i * N + 3] = carry.w;
                }
            }
            upd(carry, tv[j]);
        }
    }
}

template <int LC>
static void run_all(const float* x, float* out, float* mask_out, void* d_ws,
                    hipStream_t stream) {
    constexpr int C = L / LC;
    floatx4*      tail = (floatx4*)d_ws;
    unsigned int* fo   = (unsigned int*)((char*)d_ws + (size_t)B * C * N * 4);
    k_prefix<LC><<<B * C / CPB, 256, 0, stream>>>((const floatx4*)x,
                                                  (floatx4*)out,
                                                  (floatx4*)mask_out,
                                                  tail, fo);
    k_scan_patch<LC><<<B, 64, 0, stream>>>(tail, fo, out);
}

extern "C" void kernel_launch(void* const* d_in, const int* in_sizes, int n_in,
                              void* d_out, int out_size, void* d_ws, size_t ws_size,
                              hipStream_t stream) {
    const float* x = (const float*)d_in[0];
    const long n_total = (long)B * L * N;  // 33,554,432

    float* out = (float*)d_out;
    float* mask_out = ((long)out_size >= 2 * n_total) ? out + n_total : nullptr;

    // ws need per LC: tails (B*C*N*4 B) + first-obs (B*C*N B) = B*C*N*5.
    auto need = [](int C) { return (size_t)B * C * N * 5; };

    if (ws_size >= need(L / 64)) {
        // LC=64 (C=64): 512 blocks / 2048 waves, 64 KB contiguous per
        // wave-stream, 2.6 MB ws. The few-long-streams regime.
        run_all<64>(x, out, mask_out, d_ws, stream);
    } else if (ws_size >= need(L / 128)) {
        run_all<128>(x, out, mask_out, d_ws, stream);  // 1.3 MB
    } else {
        run_all<1024>(x, out, mask_out, d_ws, stream); // 160 KB, last resort
    }
}